// Round 1
// baseline (3152.615 us; speedup 1.0000x reference)
//
#include <hip/hip_runtime.h>

#define NN 4096
#define DD 64
#define NBLK 256
#define NTHR 1024
#define NWAVE 16
#define ITERS 50

typedef __attribute__((ext_vector_type(8))) short short8;
typedef __attribute__((ext_vector_type(4))) float f32x4;

#define C2f     0.4808983469629878f   /* 1/(eps*ln2), eps=3 */
#define EPSLN2f 2.0794415416798359f   /* eps*ln2 */
#define EPSLNNf 24.95329850015803f    /* eps*ln(4096) = 36*ln2 */

__device__ inline unsigned fkey(float f) {
  unsigned u = __float_as_uint(f);
  return (u & 0x80000000u) ? ~u : (u | 0x80000000u);
}
__device__ inline float fdec(unsigned k) {
  return (k & 0x80000000u) ? __uint_as_float(k & 0x7fffffffu) : __uint_as_float(~k);
}
__device__ inline short bf16_of(float f) {
  unsigned u = __float_as_uint(f);
  u += 0x7fffu + ((u >> 16) & 1u);   // RTNE, inputs finite
  return (short)(u >> 16);
}

// Monotonic grid barrier: release fence + device-scope atomic arrive + acquire spin.
__device__ inline void gridbar(unsigned* bar, unsigned target, int tid) {
  __syncthreads();
  if (tid == 0) {
    __threadfence();                       // agent release: L2 writeback (cross-XCD)
    atomicAdd(bar, 1u);
    while (__hip_atomic_load(bar, __ATOMIC_ACQUIRE, __HIP_MEMORY_SCOPE_AGENT) < target)
      __builtin_amdgcn_s_sleep(1);
  }
  __syncthreads();
}

// One MFMA tile pass tracking per-row max of dot(A_row, B_row) over all 4096 B rows.
__device__ inline void maxpass(const short* __restrict__ Ab, const short* __restrict__ Bb,
                               int i0, float* __restrict__ outmax,
                               int wave, int lane, int tid, float* red) {
  const short* ap = Ab + ((i0 + (lane & 15)) << 6) + ((lane >> 4) << 3);
  short8 a0 = *(const short8*)ap;
  short8 a1 = *(const short8*)(ap + 32);
  float m[4] = {-3.0e38f, -3.0e38f, -3.0e38f, -3.0e38f};
  for (int t = wave; t < 256; t += NWAVE) {
    const int jb = t << 4;
    const short* bp = Bb + ((jb + (lane & 15)) << 6) + ((lane >> 4) << 3);
    short8 b0 = *(const short8*)bp;
    short8 b1 = *(const short8*)(bp + 32);
    f32x4 acc = {0.f, 0.f, 0.f, 0.f};
    acc = __builtin_amdgcn_mfma_f32_16x16x32_bf16(a0, b0, acc, 0, 0, 0);
    acc = __builtin_amdgcn_mfma_f32_16x16x32_bf16(a1, b1, acc, 0, 0, 0);
#pragma unroll
    for (int r = 0; r < 4; ++r) m[r] = fmaxf(m[r], acc[r]);
  }
#pragma unroll
  for (int o = 1; o <= 8; o <<= 1)
#pragma unroll
    for (int r = 0; r < 4; ++r) m[r] = fmaxf(m[r], __shfl_xor(m[r], o));
  if ((lane & 15) == 0)
#pragma unroll
    for (int r = 0; r < 4; ++r) red[wave * 16 + ((lane >> 4) << 2) + r] = m[r];
  __syncthreads();
  if (tid < 16) {
    float mm = -3.0e38f;
#pragma unroll
    for (int w = 0; w < NWAVE; ++w) mm = fmaxf(mm, red[w * 16 + tid]);
    outmax[i0 + tid] = mm;
  }
  __syncthreads();
}

// One Sinkhorn half-step for this block's 16 rows:
// pot_i = sqA_i - eps*ln2*(M2_i + log2(sum_j 2^(dot*c + biasc_j - M2_i))) + eps*ln(n)
__device__ inline void halfstep(const short* __restrict__ Ab, const short* __restrict__ Bb,
                                const float* __restrict__ biasIn, const float* __restrict__ rowmax,
                                const float* __restrict__ sqA, float* __restrict__ potOut,
                                float* __restrict__ biasOut,
                                unsigned* slotIn, unsigned* slotOut,
                                int i0, int wave, int lane, int tid,
                                float* red, unsigned* sh_slot) {
  if (tid == 0) *sh_slot = atomicOr(slotIn, 0u);   // device-scope coherent readback
  const short* ap = Ab + ((i0 + (lane & 15)) << 6) + ((lane >> 4) << 3);
  short8 a0 = *(const short8*)ap;
  short8 a1 = *(const short8*)(ap + 32);
  __syncthreads();
  const float maxsc = fdec(*sh_slot);
  float M2[4];
#pragma unroll
  for (int r = 0; r < 4; ++r)
    M2[r] = __builtin_fmaf(rowmax[i0 + ((lane >> 4) << 2) + r], C2f, maxsc);
  float sum[4] = {0.f, 0.f, 0.f, 0.f};
  for (int t = wave; t < 256; t += NWAVE) {
    const int jb = t << 4;
    const short* bp = Bb + ((jb + (lane & 15)) << 6) + ((lane >> 4) << 3);
    short8 b0 = *(const short8*)bp;
    short8 b1 = *(const short8*)(bp + 32);
    f32x4 acc = {0.f, 0.f, 0.f, 0.f};
    acc = __builtin_amdgcn_mfma_f32_16x16x32_bf16(a0, b0, acc, 0, 0, 0);
    acc = __builtin_amdgcn_mfma_f32_16x16x32_bf16(a1, b1, acc, 0, 0, 0);
    const float bb = biasIn[jb + (lane & 15)];
#pragma unroll
    for (int r = 0; r < 4; ++r)
      sum[r] += __builtin_amdgcn_exp2f(__builtin_fmaf(acc[r], C2f, bb - M2[r]));
  }
#pragma unroll
  for (int o = 1; o <= 8; o <<= 1)
#pragma unroll
    for (int r = 0; r < 4; ++r) sum[r] += __shfl_xor(sum[r], o);
  if ((lane & 15) == 0)
#pragma unroll
    for (int r = 0; r < 4; ++r) red[wave * 16 + ((lane >> 4) << 2) + r] = sum[r];
  __syncthreads();
  if (tid < 16) {
    const int i = i0 + tid;
    float total = 0.f;
#pragma unroll
    for (int w = 0; w < NWAVE; ++w) total += red[w * 16 + tid];
    const float M2i = __builtin_fmaf(rowmax[i], C2f, maxsc);
    const float lse2 = M2i + __builtin_amdgcn_logf(total);   // v_log_f32 = log2
    const float pot = sqA[i] - EPSLN2f * lse2 + EPSLNNf;
    potOut[i] = pot;
    const float bc = (pot - sqA[i]) * C2f;
    biasOut[i] = bc;
    atomicMax(slotOut, fkey(bc));
  }
  // trailing sync provided by the following gridbar
}

__global__ __launch_bounds__(NTHR) void sink_kernel(const float* __restrict__ X,
                                                    const float* __restrict__ Y,
                                                    float* __restrict__ out,
                                                    unsigned char* __restrict__ ws) {
  // ws layout (first 1024 bytes zeroed by host-side hipMemsetAsync each call)
  unsigned* bar   = (unsigned*)ws;                 // arrival counter
  unsigned* slots = (unsigned*)(ws + 16);          // 128 max-bias slots (ordered-uint keys)
  short* Xb = (short*)(ws + 1024);                 // 4096x64 bf16
  short* Yb = Xb + NN * DD;
  float* fb = (float*)(Yb + NN * DD);
  float* xsq   = fb;            // 0.5*|x|^2
  float* ysq   = xsq + NN;
  float* rmx   = ysq + NN;      // rowmax over j of dot(x_i, y_j)  (bf16 dots)
  float* rmy   = rmx + NN;      // rowmax over i of dot(y_j, x_i)
  float* biasG = rmy + NN;      // (g_j - ysq_j)*c   (scaled, consumed by f-phase)
  float* biasF = biasG + NN;    // (f_i - xsq_i)*c

  const int tid  = threadIdx.x;
  const int blk  = blockIdx.x;
  const int wave = tid >> 6;
  const int lane = tid & 63;
  const int i0   = blk << 4;    // this block's 16 rows

  __shared__ float red[NWAVE * 16];
  __shared__ unsigned sh_slot;

  // ---- phase 0a: bf16 conversion + 0.5*row-norms ----
  for (int idx = blk * NTHR + tid; idx < NN * DD; idx += NBLK * NTHR) {
    Xb[idx] = bf16_of(X[idx]);
    Yb[idx] = bf16_of(Y[idx]);
  }
  {
    const int gw = blk * NWAVE + wave;       // one row per wave, 4096 waves total
    float vx = X[gw * DD + lane];
    float vy = Y[gw * DD + lane];
    float sx = vx * vx, sy = vy * vy;
#pragma unroll
    for (int o = 1; o < 64; o <<= 1) { sx += __shfl_xor(sx, o); sy += __shfl_xor(sy, o); }
    if (lane == 0) { xsq[gw] = 0.5f * sx; ysq[gw] = 0.5f * sy; }
  }
  unsigned barphase = 0;
  gridbar(bar, barphase += NBLK, tid);

  // ---- phase 0b: row maxes of the bf16 dot matrix + initial bias (g=0) ----
  maxpass(Xb, Yb, i0, rmx, wave, lane, tid, red);
  maxpass(Yb, Xb, i0, rmy, wave, lane, tid, red);
  if (tid < 16) {
    const int j = i0 + tid;
    const float bc = -ysq[j] * C2f;          // (g0 - ysq)*c with g0 = 0
    biasG[j] = bc;
    atomicMax(&slots[0], fkey(bc));
  }
  gridbar(bar, barphase += NBLK, tid);

  // ---- 50 iterations: f-update then g-update ----
  float* f_out = out;
  float* g_out = out + NN;
  for (int it = 0; it < ITERS; ++it) {
    halfstep(Xb, Yb, biasG, rmx, xsq, f_out, biasF,
             &slots[2 * it], &slots[2 * it + 1], i0, wave, lane, tid, red, &sh_slot);
    gridbar(bar, barphase += NBLK, tid);
    halfstep(Yb, Xb, biasF, rmy, ysq, g_out, biasG,
             &slots[2 * it + 1], &slots[2 * it + 2], i0, wave, lane, tid, red, &sh_slot);
    if (it != ITERS - 1) gridbar(bar, barphase += NBLK, tid);
  }
}

extern "C" void kernel_launch(void* const* d_in, const int* in_sizes, int n_in,
                              void* d_out, int out_size, void* d_ws, size_t ws_size,
                              hipStream_t stream) {
  const float* X = (const float*)d_in[0];
  const float* Y = (const float*)d_in[1];
  float* out = (float*)d_out;
  unsigned char* ws = (unsigned char*)d_ws;
  hipMemsetAsync(d_ws, 0, 1024, stream);   // zero barrier counter + max-bias slots
  sink_kernel<<<dim3(NBLK), dim3(NTHR), 0, stream>>>(X, Y, out, ws);
}

// Round 2
// 2355.498 us; speedup vs baseline: 1.3384x; 1.3384x over previous
//
#include <hip/hip_runtime.h>

#define NN 4096
#define DD 64
#define NBLK 256
#define NTHR 1024
#define NWAVE 16
#define ITERS 50

typedef __attribute__((ext_vector_type(8))) short short8;
typedef __attribute__((ext_vector_type(4))) float f32x4;

#define C2f     0.4808983469629878f   /* 1/(eps*ln2), eps=3 */
#define EPSLN2f 2.0794415416798359f   /* eps*ln2 */
#define EPSLNNf 24.95329850015803f    /* eps*ln(4096) */

__device__ inline unsigned fkey(float f) {
  unsigned u = __float_as_uint(f);
  return (u & 0x80000000u) ? ~u : (u | 0x80000000u);
}
__device__ inline float fdec(unsigned k) {
  return (k & 0x80000000u) ? __uint_as_float(k & 0x7fffffffu) : __uint_as_float(~k);
}
__device__ inline short bf16_of(float f) {
  unsigned u = __float_as_uint(f);
  u += 0x7fffu + ((u >> 16) & 1u);   // RTNE, inputs finite
  return (short)(u >> 16);
}

// Drain this wave's outstanding vmem ops (release for write-through atomic stores).
__device__ inline void wait_stores() { asm volatile("s_waitcnt vmcnt(0)" ::: "memory"); }

// Relaxed LLC poll — NO acquire, so no per-poll L2 invalidation.
__device__ inline void barrier_poll(unsigned* bar, unsigned target) {
  while (__hip_atomic_load(bar, __ATOMIC_RELAXED, __HIP_MEMORY_SCOPE_AGENT) < target)
    __builtin_amdgcn_s_sleep(2);
}
// Release barrier (used ONCE, after the normal-store init phase): wbl2 then arrive.
__device__ inline void gridbar_release(unsigned* bar, unsigned target, int tid) {
  __syncthreads();
  if (tid == 0) { __threadfence(); atomicAdd(bar, 1u); barrier_poll(bar, target); }
  __syncthreads();
}
// Steady-state barrier: no fences at all (cross-block data moves via LLC atomics).
__device__ inline void gridbar_light(unsigned* bar, unsigned target, int tid) {
  __syncthreads();
  if (tid == 0) { atomicAdd(bar, 1u); barrier_poll(bar, target); }
  __syncthreads();
}

// Per-row max of dot(A_row, B_j) over all 4096 j (bf16 dots), result to block-local LDS.
__device__ inline void maxpass(const short* __restrict__ Ab, const short* __restrict__ Bb,
                               int i0, float* __restrict__ sh_rm,
                               int wave, int lane, int tid, float* red) {
  const short* ap = Ab + ((i0 + (lane & 15)) << 6) + ((lane >> 4) << 3);
  short8 a0 = *(const short8*)ap;
  short8 a1 = *(const short8*)(ap + 32);
  float m[4] = {-3.0e38f, -3.0e38f, -3.0e38f, -3.0e38f};
  for (int t = wave; t < 256; t += NWAVE) {
    const int jb = t << 4;
    const short* bp = Bb + ((jb + (lane & 15)) << 6) + ((lane >> 4) << 3);
    short8 b0 = *(const short8*)bp;
    short8 b1 = *(const short8*)(bp + 32);
    f32x4 acc = {0.f, 0.f, 0.f, 0.f};
    acc = __builtin_amdgcn_mfma_f32_16x16x32_bf16(a0, b0, acc, 0, 0, 0);
    acc = __builtin_amdgcn_mfma_f32_16x16x32_bf16(a1, b1, acc, 0, 0, 0);
#pragma unroll
    for (int r = 0; r < 4; ++r) m[r] = fmaxf(m[r], acc[r]);
  }
#pragma unroll
  for (int o = 1; o <= 8; o <<= 1)
#pragma unroll
    for (int r = 0; r < 4; ++r) m[r] = fmaxf(m[r], __shfl_xor(m[r], o));
  if ((lane & 15) == 0)
#pragma unroll
    for (int r = 0; r < 4; ++r) red[wave * 16 + ((lane >> 4) << 2) + r] = m[r];
  __syncthreads();
  if (tid < 16) {
    float mm = -3.0e38f;
#pragma unroll
    for (int w = 0; w < NWAVE; ++w) mm = fmaxf(mm, red[w * 16 + tid]);
    sh_rm[tid] = mm;
  }
  __syncthreads();
}

// One Sinkhorn half-step for this block's 16 rows.
__device__ inline void halfstep(const short* __restrict__ Bb,
                                short8 a0, short8 a1,
                                float* biasIn, float* biasOut,
                                const float* sh_rm, const float* sh_sq,
                                unsigned* slotIn, unsigned* slotOut,
                                float* __restrict__ potOut, bool writeOut,
                                int i0, int wave, int lane, int tid,
                                float* red, float* bias_lds, unsigned* sh_slot) {
  if (tid == 0) *sh_slot = atomicOr(slotIn, 0u);      // LLC-coherent readback
#pragma unroll
  for (int k = 0; k < 4; ++k) {                       // stage bias via LLC (bypass L1/L2)
    const int j = tid + k * NTHR;
    bias_lds[j] = __hip_atomic_load(biasIn + j, __ATOMIC_RELAXED, __HIP_MEMORY_SCOPE_AGENT);
  }
  __syncthreads();
  const float maxsc = fdec(*sh_slot);
  float M2[4];
#pragma unroll
  for (int r = 0; r < 4; ++r)
    M2[r] = __builtin_fmaf(sh_rm[((lane >> 4) << 2) + r], C2f, maxsc);
  float sum[4] = {0.f, 0.f, 0.f, 0.f};
  for (int t = wave; t < 256; t += NWAVE) {
    const int jb = t << 4;
    const short* bp = Bb + ((jb + (lane & 15)) << 6) + ((lane >> 4) << 3);
    short8 b0 = *(const short8*)bp;
    short8 b1 = *(const short8*)(bp + 32);
    f32x4 acc = {0.f, 0.f, 0.f, 0.f};
    acc = __builtin_amdgcn_mfma_f32_16x16x32_bf16(a0, b0, acc, 0, 0, 0);
    acc = __builtin_amdgcn_mfma_f32_16x16x32_bf16(a1, b1, acc, 0, 0, 0);
    const float bb = bias_lds[jb + (lane & 15)];
#pragma unroll
    for (int r = 0; r < 4; ++r)
      sum[r] += __builtin_amdgcn_exp2f(__builtin_fmaf(acc[r], C2f, bb - M2[r]));
  }
#pragma unroll
  for (int o = 1; o <= 8; o <<= 1)
#pragma unroll
    for (int r = 0; r < 4; ++r) sum[r] += __shfl_xor(sum[r], o);
  if ((lane & 15) == 0)
#pragma unroll
    for (int r = 0; r < 4; ++r) red[wave * 16 + ((lane >> 4) << 2) + r] = sum[r];
  __syncthreads();
  float bc_red = -3.0e38f;
  if (tid < 16) {
    float total = 0.f;
#pragma unroll
    for (int w = 0; w < NWAVE; ++w) total += red[w * 16 + tid];
    const float M2i = __builtin_fmaf(sh_rm[tid], C2f, maxsc);
    const float lse2 = M2i + __builtin_amdgcn_logf(total);   // v_log_f32 = log2
    const float pot = sh_sq[tid] - EPSLN2f * lse2 + EPSLNNf;
    if (writeOut) potOut[i0 + tid] = pot;
    const float bc = (pot - sh_sq[tid]) * C2f;
    __hip_atomic_store(biasOut + i0 + tid, bc, __ATOMIC_RELAXED, __HIP_MEMORY_SCOPE_AGENT);
    bc_red = bc;
  }
  if (wave == 0) {                     // 16 lanes -> 1 RMW per block (was 16)
#pragma unroll
    for (int o = 1; o <= 8; o <<= 1) bc_red = fmaxf(bc_red, __shfl_xor(bc_red, o));
    if (lane == 0) atomicMax(slotOut, fkey(bc_red));
  }
  wait_stores();                       // release: stores at LLC before the arrival add
}

__global__ __launch_bounds__(NTHR) void sink_kernel(const float* __restrict__ X,
                                                    const float* __restrict__ Y,
                                                    float* __restrict__ out,
                                                    unsigned char* __restrict__ ws) {
  unsigned* bar   = (unsigned*)ws;          // arrival counter (monotonic)
  unsigned* slots = (unsigned*)(ws + 16);   // 101 max-bias slots (ordered-uint keys)
  short* Xb = (short*)(ws + 1024);          // 4096x64 bf16
  short* Yb = Xb + NN * DD;
  float* bG = (float*)(Yb + NN * DD);       // (g - ysq)*c, ping
  float* bF = bG + NN;                      // (f - xsq)*c, pong

  const int tid  = threadIdx.x;
  const int blk  = blockIdx.x;
  const int wave = tid >> 6;
  const int lane = tid & 63;
  const int i0   = blk << 4;

  __shared__ float red[NWAVE * 16];
  __shared__ float bias_lds[NN];
  __shared__ float sh_rmx[16], sh_rmy[16], sh_xsq[16], sh_ysq[16];
  __shared__ unsigned sh_slot;

  // ---- init: bf16 conversion (normal stores) + block-local 0.5*row-norms ----
  for (int idx = blk * NTHR + tid; idx < NN * DD; idx += NBLK * NTHR) {
    Xb[idx] = bf16_of(X[idx]);
    Yb[idx] = bf16_of(Y[idx]);
  }
  {
    const int row = i0 + wave;               // 16 waves = this block's 16 rows
    float vx = X[row * DD + lane];
    float vy = Y[row * DD + lane];
    float sx = vx * vx, sy = vy * vy;
#pragma unroll
    for (int o = 1; o < 64; o <<= 1) { sx += __shfl_xor(sx, o); sy += __shfl_xor(sy, o); }
    if (lane == 0) { sh_xsq[wave] = 0.5f * sx; sh_ysq[wave] = 0.5f * sy; }
  }
  unsigned bp = 0;
  gridbar_release(bar, bp += NBLK, tid);     // the ONLY fenced barrier

  // ---- row maxes of bf16 dot matrix (block-local) + initial g-bias (g=0) ----
  maxpass(Xb, Yb, i0, sh_rmx, wave, lane, tid, red);
  maxpass(Yb, Xb, i0, sh_rmy, wave, lane, tid, red);
  float bc0 = -3.0e38f;
  if (tid < 16) {
    bc0 = -sh_ysq[tid] * C2f;
    __hip_atomic_store(bG + i0 + tid, bc0, __ATOMIC_RELAXED, __HIP_MEMORY_SCOPE_AGENT);
  }
  if (wave == 0) {
#pragma unroll
    for (int o = 1; o <= 8; o <<= 1) bc0 = fmaxf(bc0, __shfl_xor(bc0, o));
    if (lane == 0) atomicMax(&slots[0], fkey(bc0));
  }
  wait_stores();
  gridbar_light(bar, bp += NBLK, tid);

  // A-fragments are loop-invariant: load once.
  const short* apx = Xb + ((i0 + (lane & 15)) << 6) + ((lane >> 4) << 3);
  short8 ax0 = *(const short8*)apx;
  short8 ax1 = *(const short8*)(apx + 32);
  const short* apy = Yb + ((i0 + (lane & 15)) << 6) + ((lane >> 4) << 3);
  short8 ay0 = *(const short8*)apy;
  short8 ay1 = *(const short8*)(apy + 32);

  for (int it = 0; it < ITERS; ++it) {
    const bool last = (it == ITERS - 1);
    halfstep(Yb, ax0, ax1, bG, bF, sh_rmx, sh_xsq, &slots[2 * it], &slots[2 * it + 1],
             out, last, i0, wave, lane, tid, red, bias_lds, &sh_slot);
    gridbar_light(bar, bp += NBLK, tid);
    halfstep(Xb, ay0, ay1, bF, bG, sh_rmy, sh_ysq, &slots[2 * it + 1], &slots[2 * it + 2],
             out + NN, last, i0, wave, lane, tid, red, bias_lds, &sh_slot);
    if (!last) gridbar_light(bar, bp += NBLK, tid);
  }
}

extern "C" void kernel_launch(void* const* d_in, const int* in_sizes, int n_in,
                              void* d_out, int out_size, void* d_ws, size_t ws_size,
                              hipStream_t stream) {
  const float* X = (const float*)d_in[0];
  const float* Y = (const float*)d_in[1];
  float* out = (float*)d_out;
  unsigned char* ws = (unsigned char*)d_ws;
  hipMemsetAsync(d_ws, 0, 1024, stream);   // zero barrier counter + slots
  sink_kernel<<<dim3(NBLK), dim3(NTHR), 0, stream>>>(X, Y, out, ws);
}

// Round 3
// 1231.507 us; speedup vs baseline: 2.5600x; 1.9127x over previous
//
#include <hip/hip_runtime.h>

#define NN 4096
#define DD 64
#define NBLK 256
#define NTHR 1024
#define NWAVE 16
#define ITERS 50

typedef __attribute__((ext_vector_type(8))) short short8;
typedef __attribute__((ext_vector_type(4))) float f32x4;
typedef _Float16 half2v __attribute__((ext_vector_type(2)));

#define C2f     0.4808983469629878f   /* 1/(eps*ln2), eps=3 */
#define EPSLN2f 2.0794415416798359f   /* eps*ln2 */
#define EPSLNNf 24.95329850015803f    /* eps*ln(4096) */

__device__ inline short bf16_of(float f) {
  unsigned u = __float_as_uint(f);
  u += 0x7fffu + ((u >> 16) & 1u);   // RTNE, inputs finite
  return (short)(u >> 16);
}
__device__ inline void wait_vmem() { asm volatile("s_waitcnt vmcnt(0)" ::: "memory"); }

__device__ inline void pollbar(unsigned* bar, unsigned target) {
  while (__hip_atomic_load(bar, __ATOMIC_RELAXED, __HIP_MEMORY_SCOPE_AGENT) < target)
    __builtin_amdgcn_s_sleep(2);
}

// Two-level grid barrier: 32 arrivals per padded group counter, 8 leader RMWs on bar.
// All cross-block data moves via LLC (sc1) atomics, so no fences in steady state.
template <bool FENCE>
__device__ inline void gridbar(unsigned* bar, unsigned* cnt, int grp, unsigned phase, int tid) {
  wait_vmem();                          // own stores complete (at L2 / LLC)
  __syncthreads();
  if (tid == 0) {
    if (FENCE) __threadfence();         // init only: wbl2 so normal stores reach LLC
    unsigned old = atomicAdd(&cnt[grp << 5], 1u);
    if (old == (phase << 5) - 1u) atomicAdd(bar, 1u);
    pollbar(bar, phase << 3);
  }
  __syncthreads();
}

// Build this block's 16 rows of the dot matrix vs all 4096 B rows; pack f16 to regs.
__device__ __forceinline__ void build(short8 a0, short8 a1, const short* __restrict__ Bb,
                                      unsigned (&S)[32], int wave, int lane) {
#pragma unroll
  for (int k = 0; k < 16; ++k) {
    const int jb = (wave + (k << 4)) << 4;
    const short* bp = Bb + ((jb + (lane & 15)) << 6) + ((lane >> 4) << 3);
    short8 b0 = *(const short8*)bp;
    short8 b1 = *(const short8*)(bp + 32);
    f32x4 acc = {0.f, 0.f, 0.f, 0.f};
    acc = __builtin_amdgcn_mfma_f32_16x16x32_bf16(a0, b0, acc, 0, 0, 0);
    acc = __builtin_amdgcn_mfma_f32_16x16x32_bf16(a1, b1, acc, 0, 0, 0);
    S[2 * k]     = __builtin_bit_cast(unsigned, __builtin_amdgcn_cvt_pkrtz(acc[0], acc[1]));
    S[2 * k + 1] = __builtin_bit_cast(unsigned, __builtin_amdgcn_cvt_pkrtz(acc[2], acc[3]));
  }
}

// One Sinkhorn half-step from register-cached S. No max-shift: exp2 args are
// bounded (|dot|<=~45 -> args in [-49, +30]), totals <= ~2^27, all safely fp32.
__device__ __forceinline__ void halfstep(const unsigned (&S)[32],
                                         const float* __restrict__ biasIn,
                                         float* __restrict__ biasOut,
                                         const float* sh_sq,
                                         float* __restrict__ potOut, bool writeOut,
                                         int i0, int wave, int lane, int tid, float* red) {
  float bb[16];
#pragma unroll
  for (int k = 0; k < 16; ++k) {        // 16 independent LLC loads, issued back-to-back
    const int jb = (wave + (k << 4)) << 4;
    bb[k] = __hip_atomic_load(biasIn + jb + (lane & 15), __ATOMIC_RELAXED,
                              __HIP_MEMORY_SCOPE_AGENT);
  }
  float sum[4] = {0.f, 0.f, 0.f, 0.f};
#pragma unroll
  for (int k = 0; k < 16; ++k) {
    half2v lo = __builtin_bit_cast(half2v, S[2 * k]);
    half2v hi = __builtin_bit_cast(half2v, S[2 * k + 1]);
    sum[0] += __builtin_amdgcn_exp2f(__builtin_fmaf((float)lo[0], C2f, bb[k]));
    sum[1] += __builtin_amdgcn_exp2f(__builtin_fmaf((float)lo[1], C2f, bb[k]));
    sum[2] += __builtin_amdgcn_exp2f(__builtin_fmaf((float)hi[0], C2f, bb[k]));
    sum[3] += __builtin_amdgcn_exp2f(__builtin_fmaf((float)hi[1], C2f, bb[k]));
  }
#pragma unroll
  for (int o = 1; o <= 8; o <<= 1)
#pragma unroll
    for (int r = 0; r < 4; ++r) sum[r] += __shfl_xor(sum[r], o);
  if ((lane & 15) == 0)
#pragma unroll
    for (int r = 0; r < 4; ++r) red[wave * 16 + ((lane >> 4) << 2) + r] = sum[r];
  __syncthreads();
  if (tid < 16) {
    float total = 0.f;
#pragma unroll
    for (int w = 0; w < NWAVE; ++w) total += red[w * 16 + tid];
    const float pot = sh_sq[tid] - EPSLN2f * __builtin_amdgcn_logf(total) + EPSLNNf;
    if (writeOut) potOut[i0 + tid] = pot;
    __hip_atomic_store(biasOut + i0 + tid, (pot - sh_sq[tid]) * C2f,
                       __ATOMIC_RELAXED, __HIP_MEMORY_SCOPE_AGENT);
  }
  // vmem drain happens inside the following gridbar
}

__global__ __launch_bounds__(NTHR) void sink_kernel(const float* __restrict__ X,
                                                    const float* __restrict__ Y,
                                                    float* __restrict__ out,
                                                    unsigned char* __restrict__ ws) {
  unsigned* bar = (unsigned*)ws;            // global arrival counter (8/phase)
  unsigned* cnt = (unsigned*)(ws + 128);    // 8 group counters, 128B apart
  short* Xb = (short*)(ws + 4096);          // 4096x64 bf16
  short* Yb = Xb + NN * DD;
  float* bG = (float*)(Yb + NN * DD);       // (g - ysq)*c
  float* bF = bG + NN;                      // (f - xsq)*c

  const int tid  = threadIdx.x;
  const int blk  = blockIdx.x;
  const int wave = tid >> 6;
  const int lane = tid & 63;
  const int i0   = blk << 4;
  const int grp  = blk >> 5;                // 8 groups of 32 blocks

  __shared__ float red[NWAVE * 16];
  __shared__ float sh_xsq[16], sh_ysq[16];

  // ---- init: bf16 conversion (1 elem/thread) + block-local 0.5*row-norms ----
  {
    const int idx = blk * NTHR + tid;
    Xb[idx] = bf16_of(X[idx]);
    Yb[idx] = bf16_of(Y[idx]);
  }
  {
    const int row = i0 + wave;
    float vx = X[row * DD + lane];
    float vy = Y[row * DD + lane];
    float sx = vx * vx, sy = vy * vy;
#pragma unroll
    for (int o = 1; o < 64; o <<= 1) { sx += __shfl_xor(sx, o); sy += __shfl_xor(sy, o); }
    if (lane == 0) { sh_xsq[wave] = 0.5f * sx; sh_ysq[wave] = 0.5f * sy; }
  }
  unsigned ph = 1;
  gridbar<true>(bar, cnt, grp, ph, tid);    // the ONLY fenced barrier

  // ---- build register-cached S (f16-packed): S_f = X_blk . Y^T, S_g = Y_blk . X^T ----
  const short* apx = Xb + ((i0 + (lane & 15)) << 6) + ((lane >> 4) << 3);
  short8 ax0 = *(const short8*)apx;
  short8 ax1 = *(const short8*)(apx + 32);
  const short* apy = Yb + ((i0 + (lane & 15)) << 6) + ((lane >> 4) << 3);
  short8 ay0 = *(const short8*)apy;
  short8 ay1 = *(const short8*)(apy + 32);
  unsigned sf[32], sg[32];
  build(ax0, ax1, Yb, sf, wave, lane);
  build(ay0, ay1, Xb, sg, wave, lane);

  if (tid < 16)                             // initial g-bias (g0 = 0)
    __hip_atomic_store(bG + i0 + tid, -sh_ysq[tid] * C2f,
                       __ATOMIC_RELAXED, __HIP_MEMORY_SCOPE_AGENT);
  ++ph;
  gridbar<false>(bar, cnt, grp, ph, tid);

  // ---- 50 iterations, 100 half-steps, register-resident S ----
  for (int it = 0; it < ITERS; ++it) {
    const bool last = (it == ITERS - 1);
    halfstep(sf, bG, bF, sh_xsq, out, last, i0, wave, lane, tid, red);
    ++ph;
    gridbar<false>(bar, cnt, grp, ph, tid);
    halfstep(sg, bF, bG, sh_ysq, out + NN, last, i0, wave, lane, tid, red);
    if (!last) { ++ph; gridbar<false>(bar, cnt, grp, ph, tid); }
  }
}

extern "C" void kernel_launch(void* const* d_in, const int* in_sizes, int n_in,
                              void* d_out, int out_size, void* d_ws, size_t ws_size,
                              hipStream_t stream) {
  const float* X = (const float*)d_in[0];
  const float* Y = (const float*)d_in[1];
  float* out = (float*)d_out;
  unsigned char* ws = (unsigned char*)d_ws;
  hipMemsetAsync(d_ws, 0, 2048, stream);    // zero barrier + group counters
  sink_kernel<<<dim3(NBLK), dim3(NTHR), 0, stream>>>(X, Y, out, ws);
}

// Round 4
// 1202.326 us; speedup vs baseline: 2.6221x; 1.0243x over previous
//
#include <hip/hip_runtime.h>

#define NN 4096
#define DD 64
#define NBLK 256
#define NTHR 1024
#define NWAVE 16
#define ITERS 50

typedef __attribute__((ext_vector_type(8))) short short8;
typedef __attribute__((ext_vector_type(4))) float f32x4;
typedef _Float16 half2v __attribute__((ext_vector_type(2)));

#define C2f     0.4808983469629878f   /* 1/(eps*ln2), eps=3 */
#define EPSLN2f 2.0794415416798359f   /* eps*ln2 */
#define EPSLNNf 24.95329850015803f    /* eps*ln(4096) */

#define LLC_LD(p) __hip_atomic_load((p), __ATOMIC_RELAXED, __HIP_MEMORY_SCOPE_AGENT)
#define LLC_ST(p, v) __hip_atomic_store((p), (v), __ATOMIC_RELAXED, __HIP_MEMORY_SCOPE_AGENT)

__device__ inline short bf16_of(float f) {
  unsigned u = __float_as_uint(f);
  u += 0x7fffu + ((u >> 16) & 1u);   // RTNE, inputs finite
  return (short)(u >> 16);
}
__device__ inline void wait_vmem() { asm volatile("s_waitcnt vmcnt(0)" ::: "memory"); }

__device__ inline void pollbar(unsigned* bar, unsigned target) {
  while (__hip_atomic_load(bar, __ATOMIC_RELAXED, __HIP_MEMORY_SCOPE_AGENT) < target)
    __builtin_amdgcn_s_sleep(2);
}

// Two-level grid barrier: 32 arrivals per padded group counter, 8 leader RMWs on bar.
// Cross-block data moves via LLC (sc1) atomics, so no cache fences in steady state.
template <bool FENCE>
__device__ inline void gridbar(unsigned* bar, unsigned* cnt, int grp, unsigned phase, int tid) {
  wait_vmem();                          // own LLC stores complete before arrival
  __syncthreads();
  if (tid == 0) {
    if (FENCE) __threadfence();         // init only: writeback normal stores
    unsigned old = atomicAdd(&cnt[grp << 5], 1u);
    if (old == (phase << 5) - 1u) atomicAdd(bar, 1u);
    pollbar(bar, phase << 3);
  }
  __syncthreads();
}

// Build this block's 16 rows of the dot matrix vs all 4096 B rows; pack f16 to regs.
__device__ __forceinline__ void build(short8 a0, short8 a1, const short* __restrict__ Bb,
                                      unsigned (&S)[32], int wave, int lane) {
#pragma unroll
  for (int k = 0; k < 16; ++k) {
    const int jb = (wave << 4) + (k << 8);
    const short* bp = Bb + ((jb + (lane & 15)) << 6) + ((lane >> 4) << 3);
    short8 b0 = *(const short8*)bp;
    short8 b1 = *(const short8*)(bp + 32);
    f32x4 acc = {0.f, 0.f, 0.f, 0.f};
    acc = __builtin_amdgcn_mfma_f32_16x16x32_bf16(a0, b0, acc, 0, 0, 0);
    acc = __builtin_amdgcn_mfma_f32_16x16x32_bf16(a1, b1, acc, 0, 0, 0);
    S[2 * k]     = __builtin_bit_cast(unsigned, __builtin_amdgcn_cvt_pkrtz(acc[0], acc[1]));
    S[2 * k + 1] = __builtin_bit_cast(unsigned, __builtin_amdgcn_cvt_pkrtz(acc[2], acc[3]));
  }
}

// One Sinkhorn half-step from register-cached S, bias staged block-wide into LDS.
// No max-shift needed: exp2 args bounded (|dot|<~45 -> args in [-49,+30]), fp32-safe.
__device__ __forceinline__ void halfstep(const unsigned (&S)[32],
                                         const float* __restrict__ biasIn,
                                         float* __restrict__ biasOut,
                                         const float* sh_sq,
                                         float* __restrict__ potOut, bool writeOut,
                                         int i0, int wave, int lane, int tid,
                                         float* red, float* bias_lds) {
  // stage 4096-float bias vector: 4 coalesced LLC loads/thread -> LDS
  float t0 = LLC_LD(biasIn + tid);
  float t1 = LLC_LD(biasIn + tid + 1024);
  float t2 = LLC_LD(biasIn + tid + 2048);
  float t3 = LLC_LD(biasIn + tid + 3072);
  bias_lds[tid]        = t0;
  bias_lds[tid + 1024] = t1;
  bias_lds[tid + 2048] = t2;
  bias_lds[tid + 3072] = t3;
  __syncthreads();
  const int c0 = (wave << 4) + (lane & 15);
  float sum[4] = {0.f, 0.f, 0.f, 0.f};
#pragma unroll
  for (int k = 0; k < 16; ++k) {
    const float bb = bias_lds[c0 + (k << 8)];      // 4-way broadcast, conflict-free
    half2v lo = __builtin_bit_cast(half2v, S[2 * k]);
    half2v hi = __builtin_bit_cast(half2v, S[2 * k + 1]);
    sum[0] += __builtin_amdgcn_exp2f(__builtin_fmaf((float)lo[0], C2f, bb));
    sum[1] += __builtin_amdgcn_exp2f(__builtin_fmaf((float)lo[1], C2f, bb));
    sum[2] += __builtin_amdgcn_exp2f(__builtin_fmaf((float)hi[0], C2f, bb));
    sum[3] += __builtin_amdgcn_exp2f(__builtin_fmaf((float)hi[1], C2f, bb));
  }
#pragma unroll
  for (int o = 1; o <= 8; o <<= 1)
#pragma unroll
    for (int r = 0; r < 4; ++r) sum[r] += __shfl_xor(sum[r], o);
  if ((lane & 15) == 0)
#pragma unroll
    for (int r = 0; r < 4; ++r) red[wave * 16 + ((lane >> 4) << 2) + r] = sum[r];
  __syncthreads();
  if (tid < 16) {
    float total = 0.f;
#pragma unroll
    for (int w = 0; w < NWAVE; ++w) total += red[w * 16 + tid];
    const float pot = sh_sq[tid] - EPSLN2f * __builtin_amdgcn_logf(total) + EPSLNNf;
    if (writeOut) potOut[i0 + tid] = pot;
    LLC_ST(biasOut + i0 + tid, (pot - sh_sq[tid]) * C2f);
  }
  // vmem drain happens inside the following gridbar
}

__global__ __launch_bounds__(NTHR, 4) void sink_kernel(const float* __restrict__ X,
                                                       const float* __restrict__ Y,
                                                       float* __restrict__ out,
                                                       unsigned char* __restrict__ ws) {
  unsigned* bar = (unsigned*)ws;            // global arrival counter (8/phase)
  unsigned* cnt = (unsigned*)(ws + 128);    // 8 group counters, 128B apart
  short* Xb = (short*)(ws + 4096);          // 4096x64 bf16
  short* Yb = Xb + NN * DD;
  float* bG = (float*)(Yb + NN * DD);       // (g - ysq)*c
  float* bF = bG + NN;                      // (f - xsq)*c

  const int tid  = threadIdx.x;
  const int blk  = blockIdx.x;
  const int wave = tid >> 6;
  const int lane = tid & 63;
  const int i0   = blk << 4;
  const int grp  = blk >> 5;                // 8 groups of 32 blocks

  __shared__ float bias_lds[NN];            // 16 KB staged bias
  __shared__ float red[NWAVE * 16];
  __shared__ float sh_xsq[16], sh_ysq[16];

  // ---- init: bf16 conversion (1 elem/thread) + block-local 0.5*row-norms ----
  {
    const int idx = blk * NTHR + tid;
    Xb[idx] = bf16_of(X[idx]);
    Yb[idx] = bf16_of(Y[idx]);
  }
  {
    const int row = i0 + wave;
    float vx = X[row * DD + lane];
    float vy = Y[row * DD + lane];
    float sx = vx * vx, sy = vy * vy;
#pragma unroll
    for (int o = 1; o < 64; o <<= 1) { sx += __shfl_xor(sx, o); sy += __shfl_xor(sy, o); }
    if (lane == 0) { sh_xsq[wave] = 0.5f * sx; sh_ysq[wave] = 0.5f * sy; }
  }
  unsigned ph = 1;
  gridbar<true>(bar, cnt, grp, ph, tid);    // the ONLY fenced barrier

  // ---- register-cached S (f16-packed): S_f = X_blk . Y^T, S_g = Y_blk . X^T ----
  const short* apx = Xb + ((i0 + (lane & 15)) << 6) + ((lane >> 4) << 3);
  short8 ax0 = *(const short8*)apx;
  short8 ax1 = *(const short8*)(apx + 32);
  const short* apy = Yb + ((i0 + (lane & 15)) << 6) + ((lane >> 4) << 3);
  short8 ay0 = *(const short8*)apy;
  short8 ay1 = *(const short8*)(apy + 32);
  unsigned sf[32], sg[32];
  build(ax0, ax1, Yb, sf, wave, lane);
  build(ay0, ay1, Xb, sg, wave, lane);

  if (tid < 16)                             // initial g-bias (g0 = 0)
    LLC_ST(bG + i0 + tid, -sh_ysq[tid] * C2f);
  ++ph;
  gridbar<false>(bar, cnt, grp, ph, tid);

  // ---- 50 iterations, 100 half-steps, register-resident S ----
  for (int it = 0; it < ITERS; ++it) {
    const bool last = (it == ITERS - 1);
    halfstep(sf, bG, bF, sh_xsq, out, last, i0, wave, lane, tid, red, bias_lds);
    ++ph;
    gridbar<false>(bar, cnt, grp, ph, tid);
    halfstep(sg, bF, bG, sh_ysq, out + NN, last, i0, wave, lane, tid, red, bias_lds);
    if (!last) { ++ph; gridbar<false>(bar, cnt, grp, ph, tid); }
  }
}

extern "C" void kernel_launch(void* const* d_in, const int* in_sizes, int n_in,
                              void* d_out, int out_size, void* d_ws, size_t ws_size,
                              hipStream_t stream) {
  const float* X = (const float*)d_in[0];
  const float* Y = (const float*)d_in[1];
  float* out = (float*)d_out;
  unsigned char* ws = (unsigned char*)d_ws;
  hipMemsetAsync(d_ws, 0, 2048, stream);    // zero barrier + group counters
  sink_kernel<<<dim3(NBLK), dim3(NTHR), 0, stream>>>(X, Y, out, ws);
}

// Round 5
// 1186.195 us; speedup vs baseline: 2.6578x; 1.0136x over previous
//
#include <hip/hip_runtime.h>

#define NN 4096
#define DD 64
#define NBLK 256
#define NTHR 1024
#define NWAVE 16
#define ITERS 50

typedef __attribute__((ext_vector_type(8))) short short8;
typedef __attribute__((ext_vector_type(4))) float f32x4;
typedef _Float16 half2v __attribute__((ext_vector_type(2)));
typedef unsigned uintv16 __attribute__((ext_vector_type(16)));

#define C2f     0.4808983469629878f   /* 1/(eps*ln2), eps=3 */
#define EPSLN2f 2.0794415416798359f   /* eps*ln2 */
#define EPSLNNf 24.95329850015803f    /* eps*ln(4096) */

#define LLC_LD(p) __hip_atomic_load((p), __ATOMIC_RELAXED, __HIP_MEMORY_SCOPE_AGENT)
#define LLC_ST(p, v) __hip_atomic_store((p), (v), __ATOMIC_RELAXED, __HIP_MEMORY_SCOPE_AGENT)

__device__ inline short bf16_of(float f) {
  unsigned u = __float_as_uint(f);
  u += 0x7fffu + ((u >> 16) & 1u);   // RTNE, inputs finite
  return (short)(u >> 16);
}
__device__ inline void wait_vmem() { asm volatile("s_waitcnt vmcnt(0)" ::: "memory"); }

__device__ inline void pollbar(unsigned* bar, unsigned target) {
  while (__hip_atomic_load(bar, __ATOMIC_RELAXED, __HIP_MEMORY_SCOPE_AGENT) < target)
    __builtin_amdgcn_s_sleep(2);
}

// Two-level grid barrier: 32 arrivals per padded group counter, 8 leader RMWs on bar.
// Cross-block data moves via LLC (sc1) atomics, so no cache fences in steady state.
template <bool FENCE>
__device__ inline void gridbar(unsigned* bar, unsigned* cnt, int grp, unsigned phase, int tid) {
  wait_vmem();                          // own LLC stores complete before arrival
  __syncthreads();
  if (tid == 0) {
    if (FENCE) __threadfence();         // init only: writeback normal stores
    unsigned old = atomicAdd(&cnt[grp << 5], 1u);
    if (old == (phase << 5) - 1u) atomicAdd(bar, 1u);
    pollbar(bar, phase << 3);
  }
  __syncthreads();
}

// Build this block's 16 rows of the dot matrix vs all 4096 B rows; f16-pack into
// two 16-wide uint vectors (64 f16 values / thread, constant-indexed -> registers).
__device__ __forceinline__ void build(short8 a0, short8 a1, const short* __restrict__ Bb,
                                      uintv16& S0, uintv16& S1, int wave, int lane) {
#pragma unroll
  for (int k = 0; k < 16; ++k) {
    const int jb = (wave << 4) + (k << 8);
    const short* bp = Bb + ((jb + (lane & 15)) << 6) + ((lane >> 4) << 3);
    short8 b0 = *(const short8*)bp;
    short8 b1 = *(const short8*)(bp + 32);
    f32x4 acc = {0.f, 0.f, 0.f, 0.f};
    acc = __builtin_amdgcn_mfma_f32_16x16x32_bf16(a0, b0, acc, 0, 0, 0);
    acc = __builtin_amdgcn_mfma_f32_16x16x32_bf16(a1, b1, acc, 0, 0, 0);
    const unsigned w0 = __builtin_bit_cast(unsigned, __builtin_amdgcn_cvt_pkrtz(acc[0], acc[1]));
    const unsigned w1 = __builtin_bit_cast(unsigned, __builtin_amdgcn_cvt_pkrtz(acc[2], acc[3]));
    if (k < 8) { S0[2 * k] = w0; S0[2 * k + 1] = w1; }
    else       { S1[2 * k - 16] = w0; S1[2 * k - 15] = w1; }
  }
}

// One Sinkhorn half-step from register-cached S, bias staged block-wide into LDS.
// No max-shift needed: exp2 args bounded (|dot|<~45 -> args in [-49,+30]), fp32-safe.
__device__ __forceinline__ void halfstep(const uintv16& S0, const uintv16& S1,
                                         const float* __restrict__ biasIn,
                                         float* __restrict__ biasOut,
                                         const float* sh_sq,
                                         float* __restrict__ potOut, bool writeOut,
                                         int i0, int wave, int lane, int tid,
                                         float* red, float* bias_lds) {
  // stage 4096-float bias vector: 4 coalesced LLC loads/thread -> LDS
  float t0 = LLC_LD(biasIn + tid);
  float t1 = LLC_LD(biasIn + tid + 1024);
  float t2 = LLC_LD(biasIn + tid + 2048);
  float t3 = LLC_LD(biasIn + tid + 3072);
  bias_lds[tid]        = t0;
  bias_lds[tid + 1024] = t1;
  bias_lds[tid + 2048] = t2;
  bias_lds[tid + 3072] = t3;
  __syncthreads();
  const int c0 = (wave << 4) + (lane & 15);
  float sum[4] = {0.f, 0.f, 0.f, 0.f};
#pragma unroll
  for (int k = 0; k < 16; ++k) {
    const float bb = bias_lds[c0 + (k << 8)];      // 4-way broadcast, conflict-free
    const unsigned w0 = (k < 8) ? S0[2 * k] : S1[2 * k - 16];
    const unsigned w1 = (k < 8) ? S0[2 * k + 1] : S1[2 * k - 15];
    half2v lo = __builtin_bit_cast(half2v, w0);
    half2v hi = __builtin_bit_cast(half2v, w1);
    sum[0] += __builtin_amdgcn_exp2f(__builtin_fmaf((float)lo[0], C2f, bb));
    sum[1] += __builtin_amdgcn_exp2f(__builtin_fmaf((float)lo[1], C2f, bb));
    sum[2] += __builtin_amdgcn_exp2f(__builtin_fmaf((float)hi[0], C2f, bb));
    sum[3] += __builtin_amdgcn_exp2f(__builtin_fmaf((float)hi[1], C2f, bb));
  }
#pragma unroll
  for (int o = 1; o <= 8; o <<= 1)
#pragma unroll
    for (int r = 0; r < 4; ++r) sum[r] += __shfl_xor(sum[r], o);
  if ((lane & 15) == 0)
#pragma unroll
    for (int r = 0; r < 4; ++r) red[wave * 16 + ((lane >> 4) << 2) + r] = sum[r];
  __syncthreads();
  if (tid < 16) {
    float total = 0.f;
#pragma unroll
    for (int w = 0; w < NWAVE; ++w) total += red[w * 16 + tid];
    const float pot = sh_sq[tid] - EPSLN2f * __builtin_amdgcn_logf(total) + EPSLNNf;
    if (writeOut) potOut[i0 + tid] = pot;
    LLC_ST(biasOut + i0 + tid, (pot - sh_sq[tid]) * C2f);
  }
  // vmem drain happens inside the following gridbar
}

__global__ __launch_bounds__(NTHR)
__attribute__((amdgpu_waves_per_eu(4, 4)))   // pin 4 waves/EU -> 128-VGPR budget, no spill
void sink_kernel(const float* __restrict__ X,
                 const float* __restrict__ Y,
                 float* __restrict__ out,
                 unsigned char* __restrict__ ws) {
  unsigned* bar = (unsigned*)ws;            // global arrival counter (8/phase)
  unsigned* cnt = (unsigned*)(ws + 128);    // 8 group counters, 128B apart
  short* Xb = (short*)(ws + 4096);          // 4096x64 bf16
  short* Yb = Xb + NN * DD;
  float* bG = (float*)(Yb + NN * DD);       // (g - ysq)*c
  float* bF = bG + NN;                      // (f - xsq)*c

  const int tid  = threadIdx.x;
  const int blk  = blockIdx.x;
  const int wave = tid >> 6;
  const int lane = tid & 63;
  const int i0   = blk << 4;
  const int grp  = blk >> 5;                // 8 groups of 32 blocks

  __shared__ float bias_lds[NN];            // 16 KB staged bias
  __shared__ float red[NWAVE * 16];
  __shared__ float sh_xsq[16], sh_ysq[16];

  // ---- init: bf16 conversion (1 elem/thread) + block-local 0.5*row-norms ----
  {
    const int idx = blk * NTHR + tid;
    Xb[idx] = bf16_of(X[idx]);
    Yb[idx] = bf16_of(Y[idx]);
  }
  {
    const int row = i0 + wave;
    float vx = X[row * DD + lane];
    float vy = Y[row * DD + lane];
    float sx = vx * vx, sy = vy * vy;
#pragma unroll
    for (int o = 1; o < 64; o <<= 1) { sx += __shfl_xor(sx, o); sy += __shfl_xor(sy, o); }
    if (lane == 0) { sh_xsq[wave] = 0.5f * sx; sh_ysq[wave] = 0.5f * sy; }
  }
  unsigned ph = 1;
  gridbar<true>(bar, cnt, grp, ph, tid);    // the ONLY fenced barrier

  // ---- register-cached S (f16-packed): S_f = X_blk . Y^T, S_g = Y_blk . X^T ----
  const short* apx = Xb + ((i0 + (lane & 15)) << 6) + ((lane >> 4) << 3);
  short8 ax0 = *(const short8*)apx;
  short8 ax1 = *(const short8*)(apx + 32);
  const short* apy = Yb + ((i0 + (lane & 15)) << 6) + ((lane >> 4) << 3);
  short8 ay0 = *(const short8*)apy;
  short8 ay1 = *(const short8*)(apy + 32);
  uintv16 sf0, sf1, sg0, sg1;
  build(ax0, ax1, Yb, sf0, sf1, wave, lane);
  build(ay0, ay1, Xb, sg0, sg1, wave, lane);

  if (tid < 16)                             // initial g-bias (g0 = 0)
    LLC_ST(bG + i0 + tid, -sh_ysq[tid] * C2f);
  ++ph;
  gridbar<false>(bar, cnt, grp, ph, tid);

  // ---- 50 iterations, 100 half-steps, register-resident S ----
  for (int it = 0; it < ITERS; ++it) {
    const bool last = (it == ITERS - 1);
    halfstep(sf0, sf1, bG, bF, sh_xsq, out, last, i0, wave, lane, tid, red, bias_lds);
    ++ph;
    gridbar<false>(bar, cnt, grp, ph, tid);
    halfstep(sg0, sg1, bF, bG, sh_ysq, out + NN, last, i0, wave, lane, tid, red, bias_lds);
    if (!last) { ++ph; gridbar<false>(bar, cnt, grp, ph, tid); }
  }
}

extern "C" void kernel_launch(void* const* d_in, const int* in_sizes, int n_in,
                              void* d_out, int out_size, void* d_ws, size_t ws_size,
                              hipStream_t stream) {
  const float* X = (const float*)d_in[0];
  const float* Y = (const float*)d_in[1];
  float* out = (float*)d_out;
  unsigned char* ws = (unsigned char*)d_ws;
  hipMemsetAsync(d_ws, 0, 2048, stream);    // zero barrier + group counters
  sink_kernel<<<dim3(NBLK), dim3(NTHR), 0, stream>>>(X, Y, out, ws);
}

// Round 6
// 1075.556 us; speedup vs baseline: 2.9312x; 1.1029x over previous
//
#include <hip/hip_runtime.h>

#define NN 4096
#define DD 64
#define NBLK 512      // 256 f-blocks + 256 g-blocks
#define NTHR 1024
#define NWAVE 16
#define ITERS 50

typedef __attribute__((ext_vector_type(8))) short short8;
typedef __attribute__((ext_vector_type(4))) float f32x4;
typedef _Float16 half2v __attribute__((ext_vector_type(2)));
typedef unsigned uintv16 __attribute__((ext_vector_type(16)));

#define C2f     0.4808983469629878f   /* 1/(eps*ln2), eps=3 */
#define EPSLN2f 2.0794415416798359f   /* eps*ln2 */
#define EPSLNNf 24.95329850015803f    /* eps*ln(4096) */

#define LLC_LD(p) __hip_atomic_load((p), __ATOMIC_RELAXED, __HIP_MEMORY_SCOPE_AGENT)
#define LLC_ST(p, v) __hip_atomic_store((p), (v), __ATOMIC_RELAXED, __HIP_MEMORY_SCOPE_AGENT)

__device__ inline short bf16_of(float f) {
  unsigned u = __float_as_uint(f);
  u += 0x7fffu + ((u >> 16) & 1u);   // RTNE, inputs finite
  return (short)(u >> 16);
}
__device__ inline void wait_vmem() { asm volatile("s_waitcnt vmcnt(0)" ::: "memory"); }

__device__ inline void pollbar(unsigned* bar, unsigned target) {
  while (__hip_atomic_load(bar, __ATOMIC_RELAXED, __HIP_MEMORY_SCOPE_AGENT) < target)
    __builtin_amdgcn_s_sleep(2);
}
// Two-level arrival: 32 blocks per padded group counter; group's 32nd arriver bumps bar.
__device__ inline void arrive(unsigned* cnt, int grp, unsigned* bar, unsigned phase) {
  unsigned old = atomicAdd(&cnt[grp << 5], 1u);
  if (old == (phase << 5) - 1u) atomicAdd(bar, 1u);
}

// Build this block's 16 rows of the dot matrix vs all 4096 B rows; f16-pack into
// two 16-wide uint vectors (64 f16 / thread = 32 VGPRs, constant-indexed).
__device__ __forceinline__ void build(short8 a0, short8 a1, const short* __restrict__ Bb,
                                      uintv16& S0, uintv16& S1, int wave, int lane) {
#pragma unroll
  for (int k = 0; k < 16; ++k) {
    const int jb = (wave << 4) + (k << 8);
    const short* bp = Bb + ((jb + (lane & 15)) << 6) + ((lane >> 4) << 3);
    short8 b0 = *(const short8*)bp;
    short8 b1 = *(const short8*)(bp + 32);
    f32x4 acc = {0.f, 0.f, 0.f, 0.f};
    acc = __builtin_amdgcn_mfma_f32_16x16x32_bf16(a0, b0, acc, 0, 0, 0);
    acc = __builtin_amdgcn_mfma_f32_16x16x32_bf16(a1, b1, acc, 0, 0, 0);
    const unsigned w0 = __builtin_bit_cast(unsigned, __builtin_amdgcn_cvt_pkrtz(acc[0], acc[1]));
    const unsigned w1 = __builtin_bit_cast(unsigned, __builtin_amdgcn_cvt_pkrtz(acc[2], acc[3]));
    if (k < 8) { S0[2 * k] = w0; S0[2 * k + 1] = w1; }
    else       { S1[2 * k - 16] = w0; S1[2 * k - 15] = w1; }
  }
}

// One half-step for this block's 16 rows: poll producer barrier, stage bias to LDS,
// exp2-accumulate from register-resident S, reduce, publish bias, arrive.
__device__ __forceinline__ void halfstep(const uintv16& S0, const uintv16& S1,
                                         const float* __restrict__ biasIn,
                                         float* __restrict__ biasOut,
                                         const float* sh_sq,
                                         float* __restrict__ potOut, bool writeOut,
                                         int i0, int wave, int lane, int tid,
                                         float* red, float* bias_lds,
                                         unsigned* pollB, unsigned pollTgt,
                                         unsigned* cnt, int grp, unsigned* arrB,
                                         unsigned phase) {
  if (tid == 0) pollbar(pollB, pollTgt);
  __syncthreads();                                 // gate on producer
  float t0 = LLC_LD(biasIn + tid);
  float t1 = LLC_LD(biasIn + tid + 1024);
  float t2 = LLC_LD(biasIn + tid + 2048);
  float t3 = LLC_LD(biasIn + tid + 3072);
  bias_lds[tid]        = t0;
  bias_lds[tid + 1024] = t1;
  bias_lds[tid + 2048] = t2;
  bias_lds[tid + 3072] = t3;
  __syncthreads();
  const int c0 = (wave << 4) + (lane & 15);
  float sum[4] = {0.f, 0.f, 0.f, 0.f};
#pragma unroll
  for (int k = 0; k < 16; ++k) {
    const float bb = bias_lds[c0 + (k << 8)];      // 4-way broadcast, conflict-free
    const unsigned w0 = (k < 8) ? S0[2 * k] : S1[2 * k - 16];
    const unsigned w1 = (k < 8) ? S0[2 * k + 1] : S1[2 * k - 15];
    half2v lo = __builtin_bit_cast(half2v, w0);
    half2v hi = __builtin_bit_cast(half2v, w1);
    sum[0] += __builtin_amdgcn_exp2f(__builtin_fmaf((float)lo[0], C2f, bb));
    sum[1] += __builtin_amdgcn_exp2f(__builtin_fmaf((float)lo[1], C2f, bb));
    sum[2] += __builtin_amdgcn_exp2f(__builtin_fmaf((float)hi[0], C2f, bb));
    sum[3] += __builtin_amdgcn_exp2f(__builtin_fmaf((float)hi[1], C2f, bb));
  }
#pragma unroll
  for (int o = 1; o <= 8; o <<= 1)
#pragma unroll
    for (int r = 0; r < 4; ++r) sum[r] += __shfl_xor(sum[r], o);
  if ((lane & 15) == 0)
#pragma unroll
    for (int r = 0; r < 4; ++r) red[wave * 16 + ((lane >> 4) << 2) + r] = sum[r];
  __syncthreads();
  if (tid < 16) {
    float total = 0.f;
#pragma unroll
    for (int w = 0; w < NWAVE; ++w) total += red[w * 16 + tid];
    const float pot = sh_sq[tid] - EPSLN2f * __builtin_amdgcn_logf(total) + EPSLNNf;
    if (writeOut) potOut[i0 + tid] = pot;
    LLC_ST(biasOut + i0 + tid, (pot - sh_sq[tid]) * C2f);
  }
  if (tid == 0) {             // wave0: drain own stores (incl. lanes 1..15), then arrive
    wait_vmem();
    arrive(cnt, grp, arrB, phase);
  }
}

__global__ __launch_bounds__(NTHR, 8)   // pin 8 waves/EU: 64-VGPR budget, 2 blocks/CU
void sink_kernel(const float* __restrict__ X,
                 const float* __restrict__ Y,
                 float* __restrict__ out,
                 unsigned char* __restrict__ ws) {
  unsigned* barI = (unsigned*)ws;             // init barrier counter
  unsigned* barF = (unsigned*)(ws + 128);     // f-step done (8 per phase)
  unsigned* barG = (unsigned*)(ws + 256);     // g-step done
  unsigned* cntI = (unsigned*)(ws + 512);     // 16 groups x 128B
  unsigned* cntF = (unsigned*)(ws + 2560);    // 8 groups x 128B
  unsigned* cntG = (unsigned*)(ws + 3584);    // 8 groups x 128B
  short* Xb = (short*)(ws + 8192);            // 4096x64 bf16
  short* Yb = Xb + NN * DD;
  float* bG = (float*)(Yb + NN * DD);         // (g - ysq)*c
  float* bF = bG + NN;                        // (f - xsq)*c

  const int tid  = threadIdx.x;
  const int blk  = blockIdx.x;
  const int role = blk >> 8;                  // 0 = f-rows, 1 = g-rows
  const int rb   = blk & 255;
  const int wave = tid >> 6;
  const int lane = tid & 63;
  const int i0   = rb << 4;
  const int grp  = rb >> 5;                   // 8 groups of 32 per role

  __shared__ float bias_lds[NN];              // 16 KB staged bias
  __shared__ float red[NWAVE * 16];
  __shared__ float sh_sq[16];                 // 0.5*|row|^2 for this block's 16 rows

  const float* src = role ? Y : X;
  short* dst = role ? Yb : Xb;

  // ---- init: each role converts its own matrix (1 elem/thread) + row norms ----
  dst[rb * NTHR + tid] = bf16_of(src[rb * NTHR + tid]);
  {
    const int row = i0 + wave;
    float v = src[row * DD + lane];
    float s = v * v;
#pragma unroll
    for (int o = 1; o < 64; o <<= 1) s += __shfl_xor(s, o);
    if (lane == 0) sh_sq[wave] = 0.5f * s;
  }
  __syncthreads();
  if (role == 1 && tid < 16)                  // initial g-bias (g0 = 0), pre-barrier
    LLC_ST(bG + i0 + tid, -sh_sq[tid] * C2f);
  wait_vmem();
  __syncthreads();
  if (tid == 0) {                             // the ONLY fenced barrier
    __threadfence();
    arrive(cntI, blk >> 5, barI, 1);
    pollbar(barI, 16u);
  }
  __syncthreads();

  // ---- register-cached S (f16-packed): 16 own rows x all 4096 opposite rows ----
  const short* Ab = role ? Yb : Xb;
  const short* Bb = role ? Xb : Yb;
  const short* ap = Ab + ((i0 + (lane & 15)) << 6) + ((lane >> 4) << 3);
  short8 a0 = *(const short8*)ap;
  short8 a1 = *(const short8*)(ap + 32);
  uintv16 S0, S1;
  build(a0, a1, Bb, S0, S1, wave, lane);

  const float* biasIn  = role ? bF : bG;
  float*       biasOut = role ? bG : bF;
  unsigned* pollB = role ? barF : barG;
  unsigned* arrB  = role ? barG : barF;
  unsigned* cntA  = role ? cntG : cntF;
  float* potOut = out + (role ? NN : 0);

  // f-block it: needs g_{it-1}  (barG >= 8*it);   produces barF phase it+1
  // g-block it: needs f_{it}    (barF >= 8*(it+1)); produces barG phase it+1
  for (int it = 0; it < ITERS; ++it) {
    const bool last = (it == ITERS - 1);
    const unsigned pollTgt = (unsigned)((it + role) << 3);
    halfstep(S0, S1, biasIn, biasOut, sh_sq, potOut, last,
             i0, wave, lane, tid, red, bias_lds,
             pollB, pollTgt, cntA, grp, arrB, (unsigned)(it + 1));
  }
}

extern "C" void kernel_launch(void* const* d_in, const int* in_sizes, int n_in,
                              void* d_out, int out_size, void* d_ws, size_t ws_size,
                              hipStream_t stream) {
  const float* X = (const float*)d_in[0];
  const float* Y = (const float*)d_in[1];
  float* out = (float*)d_out;
  unsigned char* ws = (unsigned char*)d_ws;
  hipMemsetAsync(d_ws, 0, 8192, stream);      // zero all barrier/group counters
  sink_kernel<<<dim3(NBLK), dim3(NTHR), 0, stream>>>(X, Y, out, ws);
}